// Round 10
// baseline (348.416 us; speedup 1.0000x reference)
//
#include <hip/hip_runtime.h>
#include <math.h>
#include <stdint.h>

#define BATCH 4
#define CH    256
#define HH    80
#define WW    80
#define HW    (HH*WW)        // 6400
#define NPIX  (BATCH*HW)     // 25600
#define KK    9
#define CO    18             // 2*K*K offset channels
#define NCHUNK 72            // 9 taps * 8 groups of 32 channels
#define NIV   36             // K=64 intervals
#define PXB   64             // pixels per k_main block
#define NBLK  (NPIX/PXB)     // 400 blocks
#define AST   72             // A LDS row stride in halves (144 B)

typedef _Float16 half8 __attribute__((ext_vector_type(8)));
typedef _Float16 half4 __attribute__((ext_vector_type(4)));
typedef float    f32x4 __attribute__((ext_vector_type(4)));

// ---------------- x NCHW f32 -> xt NHWC f16 ----------------
__global__ __launch_bounds__(256) void k_transpose_x(const float* __restrict__ x,
                                                     _Float16* __restrict__ xt) {
    __shared__ float tile[32][33];
    int b  = blockIdx.z;
    int c0 = blockIdx.y * 32;
    int p0 = blockIdx.x * 32;
    int tx = threadIdx.x;   // 0..31
    int ty = threadIdx.y;   // 0..7
    const float* xb = x + (size_t)b * CH * HW;
    #pragma unroll
    for (int i = 0; i < 32; i += 8)
        tile[ty + i][tx] = xb[(size_t)(c0 + ty + i) * HW + p0 + tx];
    __syncthreads();
    _Float16* xtb = xt + (size_t)b * HW * CH;
    #pragma unroll
    for (int i = 0; i < 32; i += 8)
        xtb[(size_t)(p0 + ty + i) * CH + c0 + tx] = (_Float16)tile[tx][ty + i];
}

// -------- combined weight pack --------
__global__ __launch_bounds__(256) void k_pack_all(const float* __restrict__ w,
                                                  const float* __restrict__ ow,
                                                  _Float16* __restrict__ wp,
                                                  _Float16* __restrict__ wpo) {
    int idx = blockIdx.x * 256 + threadIdx.x;
    if (idx < NIV * 16384) {
        int e    = idx & 7;
        int lane = (idx >> 3) & 63;
        int nn   = (idx >> 9) & 1;
        int ks   = (idx >> 10) & 1;
        int og   = (idx >> 11) & 7;
        int iv   = idx >> 14;
        int oc = og * 32 + nn * 16 + (lane & 15);
        int kl = ks * 32 + (lane >> 4) * 8 + e;
        int kg = iv * 64 + kl;
        int q  = kg >> 5;
        int tap = q >> 3;
        int c   = (q & 7) * 32 + (kg & 31);
        wp[idx] = (_Float16)w[((size_t)oc * CH + c) * KK + tap];
        return;
    }
    int idx2 = idx - NIV * 16384;
    if (idx2 >= NCHUNK * 1024) return;
    int e    = idx2 & 7;
    int lane = (idx2 >> 3) & 63;
    int nf   = (idx2 >> 9) & 1;
    int q    = idx2 >> 10;
    int oc  = nf * 16 + (lane & 15);
    int kic = (lane >> 4) * 8 + e;
    int tap = q >> 3;
    int c   = (q & 7) * 32 + kic;
    float v = (oc < CO) ? ow[((size_t)oc * CH + c) * KK + tap] : 0.f;
    wpo[idx2] = (_Float16)v;
}

// ---------------- offset conv via MFMA, barrier-free, K-split x4 ----------------
__global__ __launch_bounds__(256) void k_offset(const _Float16* __restrict__ xt,
                                                const _Float16* __restrict__ wopf,
                                                float* __restrict__ off4) {
    int t = threadIdx.x, lane = t & 63, wvi = t >> 6;
    int lm = lane & 15, kg8 = (lane >> 4) * 8;
    int ksl = blockIdx.y;
    int pixbase = blockIdx.x * 64;
    int bb = pixbase / HW;
    int apx = pixbase % HW + wvi * 16 + lm;
    int h = apx / WW, w = apx % WW;
    const _Float16* xtb = xt + (size_t)bb * HW * CH;
    f32x4 acc0 = (f32x4)0.f, acc1 = (f32x4)0.f;
    #pragma unroll
    for (int qq = 0; qq < 18; ++qq) {
        int q = ksl * 18 + qq;
        int tap = q >> 3, cg = q & 7;
        int ki = tap / 3, kj = tap % 3;
        int yy = h + ki - 1, xx = w + kj - 1;
        bool ok = (yy >= 0) && (yy < HH) && (xx >= 0) && (xx < WW);
        int yc = min(max(yy, 0), HH - 1), xc = min(max(xx, 0), WW - 1);
        half8 a = {0, 0, 0, 0, 0, 0, 0, 0};
        if (ok) a = *(const half8*)(xtb + (size_t)(yc * WW + xc) * CH + cg * 32 + kg8);
        const _Float16* wb = wopf + (size_t)q * 1024 + lane * 8;
        half8 b0 = *(const half8*)(wb);
        half8 b1 = *(const half8*)(wb + 512);
        acc0 = __builtin_amdgcn_mfma_f32_16x16x32_f16(a, b0, acc0, 0, 0, 0);
        acc1 = __builtin_amdgcn_mfma_f32_16x16x32_f16(a, b1, acc1, 0, 0, 0);
    }
    float* op = off4 + (size_t)ksl * NPIX * CO;
    int prow = (lane >> 4) * 4;
    #pragma unroll
    for (int r = 0; r < 4; ++r) {
        int pix = pixbase + wvi * 16 + prow + r;
        op[(size_t)pix * CO + lm] = acc0[r];
        if (lm < CO - 16) op[(size_t)pix * CO + 16 + lm] = acc1[r];
    }
}

// ---- shared device helper: build bilinear corner tables into LDS ----
__device__ __forceinline__ void build_corners(int t, int nthr, int pixbase,
                                              const float* __restrict__ off4,
                                              const float* __restrict__ obias,
                                              int4 (*cbl)[KK], float4 (*cwl)[KK]) {
    for (int task = t; task < PXB * KK; task += nthr) {
        int p = task / KK, tap = task - (task / KK) * KK;
        int pix = pixbase + p;
        float dy = obias[2 * tap], dx = obias[2 * tap + 1];
        #pragma unroll
        for (int ks = 0; ks < 4; ++ks) {
            dy += off4[(size_t)ks * NPIX * CO + (size_t)pix * CO + 2 * tap];
            dx += off4[(size_t)ks * NPIX * CO + (size_t)pix * CO + 2 * tap + 1];
        }
        int hw = pix % HW, hc = hw / WW, wc = hw % WW;
        int ki = tap / 3, kj = tap % 3;
        float py = dy + (float)(hc - 1 + ki);
        float px = dx + (float)(wc - 1 + kj);
        float y0f = floorf(py), x0f = floorf(px);
        float wy = py - y0f, wx = px - x0f;
        int y0 = (int)y0f, x0 = (int)x0f;
        int cb[4]; float cw[4];
        #pragma unroll
        for (int cy = 0; cy < 2; ++cy)
            #pragma unroll
            for (int cx = 0; cx < 2; ++cx) {
                int yy = y0 + cy, xx = x0 + cx;
                bool okc = (yy >= 0) && (yy < HH) && (xx >= 0) && (xx < WW);
                int yc = min(max(yy, 0), HH - 1);
                int xc = min(max(xx, 0), WW - 1);
                float wgt = (cy ? wy : 1.f - wy) * (cx ? wx : 1.f - wx);
                cb[cy * 2 + cx] = (yc * WW + xc) * CH;
                cw[cy * 2 + cx] = okc ? wgt : 0.f;
            }
        cbl[p][tap] = make_int4(cb[0], cb[1], cb[2], cb[3]);
        cwl[p][tap] = make_float4(cw[0], cw[1], cw[2], cw[3]);
    }
}

// ---- interval body: B reg-dbuf + A LDS-dbuf, one barrier ----
#define BODY(IV, IVEND, BCUR, BNXT, RBUF, WBUF)                                    \
  {                                                                                \
    __syncthreads();                                                               \
    const int iv_ = (IV);                                                          \
    half8 pre[4]; float cwa[4];                                                    \
    if (iv_ < (IVEND) - 1) {                                                       \
      const _Float16* wb = wpk4 + (size_t)(iv_ + 1) * 16384 + og * 2048 + lane * 8;\
      BNXT[0] = *(const half8*)(wb);                                               \
      BNXT[1] = *(const half8*)(wb + 512);                                         \
      BNXT[2] = *(const half8*)(wb + 1024);                                        \
      BNXT[3] = *(const half8*)(wb + 1536);                                        \
      int chunk = 2 * (iv_ + 1) + sub;                                             \
      int tap = chunk >> 3, cg = chunk & 7;                                        \
      int4 ncb = cbl[gpx][tap]; float4 ncw = cwl[gpx][tap];                        \
      pre[0] = *(const half8*)(xtb + (size_t)ncb.x + cg * 32 + ko);                \
      pre[1] = *(const half8*)(xtb + (size_t)ncb.y + cg * 32 + ko);                \
      pre[2] = *(const half8*)(xtb + (size_t)ncb.z + cg * 32 + ko);                \
      pre[3] = *(const half8*)(xtb + (size_t)ncb.w + cg * 32 + ko);                \
      cwa[0] = ncw.x; cwa[1] = ncw.y; cwa[2] = ncw.z; cwa[3] = ncw.w;              \
    }                                                                              \
    __builtin_amdgcn_s_setprio(1);                                                 \
    _Pragma("unroll")                                                              \
    for (int mm = 0; mm < 4; ++mm) {                                               \
      half8 a0 = *(const half8*)&Ab[RBUF][(mm * 16 + lm) * AST + kg8];             \
      half8 a1 = *(const half8*)&Ab[RBUF][(mm * 16 + lm) * AST + 32 + kg8];        \
      acc[mm][0] = __builtin_amdgcn_mfma_f32_16x16x32_f16(a0, BCUR[0], acc[mm][0], 0, 0, 0); \
      acc[mm][1] = __builtin_amdgcn_mfma_f32_16x16x32_f16(a0, BCUR[1], acc[mm][1], 0, 0, 0); \
      acc[mm][0] = __builtin_amdgcn_mfma_f32_16x16x32_f16(a1, BCUR[2], acc[mm][0], 0, 0, 0); \
      acc[mm][1] = __builtin_amdgcn_mfma_f32_16x16x32_f16(a1, BCUR[3], acc[mm][1], 0, 0, 0); \
    }                                                                              \
    __builtin_amdgcn_s_setprio(0);                                                 \
    if (iv_ < (IVEND) - 1) {                                                       \
      half8 v = pre[0] * (_Float16)cwa[0];                                         \
      v += pre[1] * (_Float16)cwa[1];                                              \
      v += pre[2] * (_Float16)cwa[2];                                              \
      v += pre[3] * (_Float16)cwa[3];                                              \
      *(half8*)&Ab[WBUF][gpx * AST + cq * 8] = v;                                  \
    }                                                                              \
  }

// ---------------- split-K gather+GEMM: grid (400,2), writes f16 partials ----------------
__global__ __launch_bounds__(512, 6) void k_main_sk(const _Float16* __restrict__ xt,
                                                    const _Float16* __restrict__ wpk4,
                                                    const float* __restrict__ off4,
                                                    const float* __restrict__ obias,
                                                    _Float16* __restrict__ P) {
    __shared__ _Float16 Ab[2][PXB * AST];   // 18432 B
    __shared__ int4     cbl[PXB][KK];       // 9216 B
    __shared__ float4   cwl[PXB][KK];       // 9216 B

    int t = threadIdx.x, lane = t & 63, og = t >> 6;
    int lm = lane & 15, kg8 = (lane >> 4) * 8;
    int ksl = blockIdx.y;
    int iv0 = ksl * (NIV / 2);
    int tile = ((int)blockIdx.x & 7) * (NBLK / 8) + ((int)blockIdx.x >> 3);
    int pixbase = tile * PXB;
    int bb = pixbase / HW, hw0 = pixbase % HW;
    const _Float16* xtb = xt + (size_t)bb * HW * CH;

    build_corners(t, 512, pixbase, off4, obias, cbl, cwl);
    __syncthreads();

    int gpx = t >> 3, cq = t & 7;
    int sub = cq >> 2, ko = (cq & 3) * 8;

    // prologue: B(iv0) -> regs; gather interval iv0 -> Ab[0]
    half8 bfA[4], bfB[4];
    {
        const _Float16* wb = wpk4 + (size_t)iv0 * 16384 + og * 2048 + lane * 8;
        bfA[0] = *(const half8*)(wb);
        bfA[1] = *(const half8*)(wb + 512);
        bfA[2] = *(const half8*)(wb + 1024);
        bfA[3] = *(const half8*)(wb + 1536);
    }
    {
        int chunk0 = 2 * iv0 + sub;
        int tap0 = chunk0 >> 3, cg0 = chunk0 & 7;
        int4 cb = cbl[gpx][tap0];
        float4 cw = cwl[gpx][tap0];
        half8 v = *(const half8*)(xtb + (size_t)cb.x + cg0 * 32 + ko) * (_Float16)cw.x;
        v += *(const half8*)(xtb + (size_t)cb.y + cg0 * 32 + ko) * (_Float16)cw.y;
        v += *(const half8*)(xtb + (size_t)cb.z + cg0 * 32 + ko) * (_Float16)cw.z;
        v += *(const half8*)(xtb + (size_t)cb.w + cg0 * 32 + ko) * (_Float16)cw.w;
        *(half8*)&Ab[0][gpx * AST + cq * 8] = v;
    }

    f32x4 acc[4][2];
    #pragma unroll
    for (int mm = 0; mm < 4; ++mm) {
        acc[mm][0] = (f32x4)0.f;
        acc[mm][1] = (f32x4)0.f;
    }

    int ivend = iv0 + NIV / 2;
    for (int ii = iv0; ii < ivend; ii += 2) {
        BODY(ii,     ivend, bfA, bfB, 0, 1)
        BODY(ii + 1, ivend, bfB, bfA, 1, 0)
    }

    // --- write f16 partials, NCHW-flat plane ksl ---
    _Float16* Pb = P + (size_t)ksl * NPIX * CH + (size_t)bb * CH * HW;
    #pragma unroll
    for (int nn = 0; nn < 2; ++nn) {
        int oc = og * 32 + nn * 16 + lm;
        _Float16* prow = Pb + (size_t)oc * HW + hw0;
        #pragma unroll
        for (int mm = 0; mm < 4; ++mm) {
            int pb2 = mm * 16 + (lane >> 4) * 4;
            half4 h = {(_Float16)acc[mm][nn][0], (_Float16)acc[mm][nn][1],
                       (_Float16)acc[mm][nn][2], (_Float16)acc[mm][nn][3]};
            *(half4*)&prow[pb2] = h;
        }
    }
}

// ---------------- finish: reduce halves + BN + SiLU + residual ----------------
__global__ __launch_bounds__(512) void k_finish(const _Float16* __restrict__ P,
                                                const float* __restrict__ x,
                                                const float* __restrict__ gamma,
                                                const float* __restrict__ beta,
                                                const float* __restrict__ mean,
                                                const float* __restrict__ var,
                                                float* __restrict__ out) {
    int tid = blockIdx.x * 512 + threadIdx.x;       // 819200 threads
    size_t base = (size_t)tid * 8;
    int oc = (tid / (HW / 8)) & (CH - 1);
    half8 p0 = *(const half8*)(P + base);
    half8 p1 = *(const half8*)(P + (size_t)NPIX * CH + base);
    float sc = gamma[oc] * rsqrtf(var[oc] + 1e-5f);
    float mn = mean[oc], bt = beta[oc];
    float4 x0 = *(const float4*)(x + base);
    float4 x1 = *(const float4*)(x + base + 4);
    float o[8];
    #pragma unroll
    for (int j = 0; j < 8; ++j) {
        float y = (float)p0[j] + (float)p1[j];
        float yv = (y - mn) * sc + bt;
        float s = yv * __builtin_amdgcn_rcpf(1.f + __expf(-yv));
        float xv = (j < 4) ? ((const float*)&x0)[j] : ((const float*)&x1)[j - 4];
        o[j] = xv + s;
    }
    *(float4*)(out + base)     = make_float4(o[0], o[1], o[2], o[3]);
    *(float4*)(out + base + 4) = make_float4(o[4], o[5], o[6], o[7]);
}

// ---------------- fallback: R9 fused kernel (single-pass, fused epilogue) ----------------
__global__ __launch_bounds__(512, 4) void k_main_fused(const float* __restrict__ x,
                                                       const _Float16* __restrict__ xt,
                                                       const _Float16* __restrict__ wpk4,
                                                       const float* __restrict__ off4,
                                                       const float* __restrict__ obias,
                                                       const float* __restrict__ gamma,
                                                       const float* __restrict__ beta,
                                                       const float* __restrict__ mean,
                                                       const float* __restrict__ var,
                                                       float* __restrict__ out) {
    __shared__ _Float16 Ab[2][PXB * AST];
    __shared__ int4     cbl[PXB][KK];
    __shared__ float4   cwl[PXB][KK];

    int t = threadIdx.x, lane = t & 63, og = t >> 6;
    int lm = lane & 15, kg8 = (lane >> 4) * 8;
    int tile = ((int)blockIdx.x & 7) * (NBLK / 8) + ((int)blockIdx.x >> 3);
    int pixbase = tile * PXB;
    int bb = pixbase / HW, hw0 = pixbase % HW;
    const _Float16* xtb = xt + (size_t)bb * HW * CH;

    build_corners(t, 512, pixbase, off4, obias, cbl, cwl);
    __syncthreads();

    int gpx = t >> 3, cq = t & 7;
    int sub = cq >> 2, ko = (cq & 3) * 8;

    half8 bfA[4], bfB[4];
    {
        const _Float16* wb = wpk4 + og * 2048 + lane * 8;
        bfA[0] = *(const half8*)(wb);
        bfA[1] = *(const half8*)(wb + 512);
        bfA[2] = *(const half8*)(wb + 1024);
        bfA[3] = *(const half8*)(wb + 1536);
    }
    {
        int4 cb = cbl[gpx][0];
        float4 cw = cwl[gpx][0];
        int cg = sub;
        half8 v = *(const half8*)(xtb + (size_t)cb.x + cg * 32 + ko) * (_Float16)cw.x;
        v += *(const half8*)(xtb + (size_t)cb.y + cg * 32 + ko) * (_Float16)cw.y;
        v += *(const half8*)(xtb + (size_t)cb.z + cg * 32 + ko) * (_Float16)cw.z;
        v += *(const half8*)(xtb + (size_t)cb.w + cg * 32 + ko) * (_Float16)cw.w;
        *(half8*)&Ab[0][gpx * AST + cq * 8] = v;
    }

    f32x4 acc[4][2];
    #pragma unroll
    for (int mm = 0; mm < 4; ++mm) {
        acc[mm][0] = (f32x4)0.f;
        acc[mm][1] = (f32x4)0.f;
    }

    for (int ii = 0; ii < NIV; ii += 2) {
        BODY(ii,     NIV, bfA, bfB, 0, 1)
        BODY(ii + 1, NIV, bfB, bfA, 1, 0)
    }

    const float* xb2  = x   + (size_t)bb * CH * HW;
    float*       outb = out + (size_t)bb * CH * HW;
    #pragma unroll
    for (int nn = 0; nn < 2; ++nn) {
        int oc = og * 32 + nn * 16 + lm;
        float sc = gamma[oc] * rsqrtf(var[oc] + 1e-5f);
        float mn = mean[oc], bt = beta[oc];
        const float* xr   = xb2  + (size_t)oc * HW + hw0;
        float*       orow = outb + (size_t)oc * HW + hw0;
        #pragma unroll
        for (int mm = 0; mm < 4; ++mm) {
            int pb2 = mm * 16 + (lane >> 4) * 4;
            #pragma unroll
            for (int r = 0; r < 4; ++r) {
                float yv = (acc[mm][nn][r] - mn) * sc + bt;
                float s = yv * __builtin_amdgcn_rcpf(1.f + __expf(-yv));
                orow[pb2 + r] = xr[pb2 + r] + s;
            }
        }
    }
}

extern "C" void kernel_launch(void* const* d_in, const int* in_sizes, int n_in,
                              void* d_out, int out_size, void* d_ws, size_t ws_size,
                              hipStream_t stream) {
    const float* x        = (const float*)d_in[0];
    const float* offset_w = (const float*)d_in[1];
    const float* offset_b = (const float*)d_in[2];
    const float* dcn_w    = (const float*)d_in[3];
    const float* gamma    = (const float*)d_in[4];
    const float* beta     = (const float*)d_in[5];
    const float* mean     = (const float*)d_in[6];
    const float* var      = (const float*)d_in[7];
    float* out = (float*)d_out;

    _Float16* xt   = (_Float16*)d_ws;                         // 13,107,200 B
    _Float16* wpk4 = xt + (size_t)NPIX * CH;                  //  1,179,648 B
    _Float16* wopf = wpk4 + (size_t)NIV * 16384;              //    147,456 B
    float*    off4 = (float*)(wopf + (size_t)NCHUNK * 1024);  //  7,372,800 B
    _Float16* P    = (_Float16*)(off4 + (size_t)4 * NPIX * CO); // 26,214,400 B

    const size_t NEED = 13107200ull + 1179648 + 147456 + 7372800 + 26214400;

    k_transpose_x<<<dim3(HW / 32, CH / 32, BATCH), dim3(32, 8), 0, stream>>>(x, xt);
    k_pack_all<<<(NIV * 16384 + NCHUNK * 1024 + 255) / 256, 256, 0, stream>>>(dcn_w, offset_w, wpk4, wopf);
    k_offset<<<dim3(NBLK, 4), 256, 0, stream>>>(xt, wopf, off4);

    if (ws_size >= NEED) {
        k_main_sk<<<dim3(NBLK, 2), 512, 0, stream>>>(xt, wpk4, off4, offset_b, P);
        k_finish<<<(NPIX * CH / 8 + 511) / 512, 512, 0, stream>>>(P, x, gamma, beta, mean, var, out);
    } else {
        k_main_fused<<<NBLK, 512, 0, stream>>>(x, xt, wpk4, off4, offset_b,
                                               gamma, beta, mean, var, out);
    }
}

// Round 11
// 111.359 us; speedup vs baseline: 3.1288x; 3.1288x over previous
//
#include <hip/hip_runtime.h>
#include <math.h>
#include <stdint.h>

#define BATCH 4
#define CH    256
#define HH    80
#define WW    80
#define HW    (HH*WW)        // 6400
#define NPIX  (BATCH*HW)     // 25600
#define KK    9
#define CO    18             // 2*K*K offset channels
#define NCHUNK 72            // 9 taps * 8 groups of 32 channels
#define NIV   36             // K=64 intervals
#define PXB   64             // pixels per k_main block
#define NBLK  (NPIX/PXB)     // 400 blocks
#define AST   72             // A LDS row stride in halves (144 B)

typedef _Float16 half8 __attribute__((ext_vector_type(8)));
typedef _Float16 half4 __attribute__((ext_vector_type(4)));
typedef float    f32x4 __attribute__((ext_vector_type(4)));

// ---------------- x NCHW f32 -> xt NHWC f16 ----------------
__global__ __launch_bounds__(256) void k_transpose_x(const float* __restrict__ x,
                                                     _Float16* __restrict__ xt) {
    __shared__ float tile[32][33];
    int b  = blockIdx.z;
    int c0 = blockIdx.y * 32;
    int p0 = blockIdx.x * 32;
    int tx = threadIdx.x;   // 0..31
    int ty = threadIdx.y;   // 0..7
    const float* xb = x + (size_t)b * CH * HW;
    #pragma unroll
    for (int i = 0; i < 32; i += 8)
        tile[ty + i][tx] = xb[(size_t)(c0 + ty + i) * HW + p0 + tx];
    __syncthreads();
    _Float16* xtb = xt + (size_t)b * HW * CH;
    #pragma unroll
    for (int i = 0; i < 32; i += 8)
        xtb[(size_t)(p0 + ty + i) * CH + c0 + tx] = (_Float16)tile[tx][ty + i];
}

// -------- combined weight pack --------
__global__ __launch_bounds__(256) void k_pack_all(const float* __restrict__ w,
                                                  const float* __restrict__ ow,
                                                  _Float16* __restrict__ wp,
                                                  _Float16* __restrict__ wpo) {
    int idx = blockIdx.x * 256 + threadIdx.x;
    if (idx < NIV * 16384) {
        int e    = idx & 7;
        int lane = (idx >> 3) & 63;
        int nn   = (idx >> 9) & 1;
        int ks   = (idx >> 10) & 1;
        int og   = (idx >> 11) & 7;
        int iv   = idx >> 14;
        int oc = og * 32 + nn * 16 + (lane & 15);
        int kl = ks * 32 + (lane >> 4) * 8 + e;
        int kg = iv * 64 + kl;
        int q  = kg >> 5;
        int tap = q >> 3;
        int c   = (q & 7) * 32 + (kg & 31);
        wp[idx] = (_Float16)w[((size_t)oc * CH + c) * KK + tap];
        return;
    }
    int idx2 = idx - NIV * 16384;
    if (idx2 >= NCHUNK * 1024) return;
    int e    = idx2 & 7;
    int lane = (idx2 >> 3) & 63;
    int nf   = (idx2 >> 9) & 1;
    int q    = idx2 >> 10;
    int oc  = nf * 16 + (lane & 15);
    int kic = (lane >> 4) * 8 + e;
    int tap = q >> 3;
    int c   = (q & 7) * 32 + kic;
    float v = (oc < CO) ? ow[((size_t)oc * CH + c) * KK + tap] : 0.f;
    wpo[idx2] = (_Float16)v;
}

// ---------------- offset conv via MFMA, barrier-free, K-split x4 ----------------
__global__ __launch_bounds__(256) void k_offset(const _Float16* __restrict__ xt,
                                                const _Float16* __restrict__ wopf,
                                                float* __restrict__ off4) {
    int t = threadIdx.x, lane = t & 63, wvi = t >> 6;
    int lm = lane & 15, kg8 = (lane >> 4) * 8;
    int ksl = blockIdx.y;
    int pixbase = blockIdx.x * 64;
    int bb = pixbase / HW;
    int apx = pixbase % HW + wvi * 16 + lm;
    int h = apx / WW, w = apx % WW;
    const _Float16* xtb = xt + (size_t)bb * HW * CH;
    f32x4 acc0 = (f32x4)0.f, acc1 = (f32x4)0.f;
    #pragma unroll
    for (int qq = 0; qq < 18; ++qq) {
        int q = ksl * 18 + qq;
        int tap = q >> 3, cg = q & 7;
        int ki = tap / 3, kj = tap % 3;
        int yy = h + ki - 1, xx = w + kj - 1;
        bool ok = (yy >= 0) && (yy < HH) && (xx >= 0) && (xx < WW);
        int yc = min(max(yy, 0), HH - 1), xc = min(max(xx, 0), WW - 1);
        half8 a = {0, 0, 0, 0, 0, 0, 0, 0};
        if (ok) a = *(const half8*)(xtb + (size_t)(yc * WW + xc) * CH + cg * 32 + kg8);
        const _Float16* wb = wopf + (size_t)q * 1024 + lane * 8;
        half8 b0 = *(const half8*)(wb);
        half8 b1 = *(const half8*)(wb + 512);
        acc0 = __builtin_amdgcn_mfma_f32_16x16x32_f16(a, b0, acc0, 0, 0, 0);
        acc1 = __builtin_amdgcn_mfma_f32_16x16x32_f16(a, b1, acc1, 0, 0, 0);
    }
    float* op = off4 + (size_t)ksl * NPIX * CO;
    int prow = (lane >> 4) * 4;
    #pragma unroll
    for (int r = 0; r < 4; ++r) {
        int pix = pixbase + wvi * 16 + prow + r;
        op[(size_t)pix * CO + lm] = acc0[r];
        if (lm < CO - 16) op[(size_t)pix * CO + 16 + lm] = acc1[r];
    }
}

// ---- shared device helper: build bilinear corner tables into LDS ----
__device__ __forceinline__ void build_corners(int t, int nthr, int pixbase,
                                              const float* __restrict__ off4,
                                              const float* __restrict__ obias,
                                              int4 (*cbl)[KK], float4 (*cwl)[KK]) {
    for (int task = t; task < PXB * KK; task += nthr) {
        int p = task / KK, tap = task - (task / KK) * KK;
        int pix = pixbase + p;
        float dy = obias[2 * tap], dx = obias[2 * tap + 1];
        #pragma unroll
        for (int ks = 0; ks < 4; ++ks) {
            dy += off4[(size_t)ks * NPIX * CO + (size_t)pix * CO + 2 * tap];
            dx += off4[(size_t)ks * NPIX * CO + (size_t)pix * CO + 2 * tap + 1];
        }
        int hw = pix % HW, hc = hw / WW, wc = hw % WW;
        int ki = tap / 3, kj = tap % 3;
        float py = dy + (float)(hc - 1 + ki);
        float px = dx + (float)(wc - 1 + kj);
        float y0f = floorf(py), x0f = floorf(px);
        float wy = py - y0f, wx = px - x0f;
        int y0 = (int)y0f, x0 = (int)x0f;
        int cb[4]; float cw[4];
        #pragma unroll
        for (int cy = 0; cy < 2; ++cy)
            #pragma unroll
            for (int cx = 0; cx < 2; ++cx) {
                int yy = y0 + cy, xx = x0 + cx;
                bool okc = (yy >= 0) && (yy < HH) && (xx >= 0) && (xx < WW);
                int yc = min(max(yy, 0), HH - 1);
                int xc = min(max(xx, 0), WW - 1);
                float wgt = (cy ? wy : 1.f - wy) * (cx ? wx : 1.f - wx);
                cb[cy * 2 + cx] = (yc * WW + xc) * CH;
                cw[cy * 2 + cx] = okc ? wgt : 0.f;
            }
        cbl[p][tap] = make_int4(cb[0], cb[1], cb[2], cb[3]);
        cwl[p][tap] = make_float4(cw[0], cw[1], cw[2], cw[3]);
    }
}

// ---- interval body: B reg-dbuf + A LDS-dbuf, one barrier ----
#define BODY(IV, IVEND, BCUR, BNXT, RBUF, WBUF)                                    \
  {                                                                                \
    __syncthreads();                                                               \
    const int iv_ = (IV);                                                          \
    half8 pre[4]; float cwa[4];                                                    \
    if (iv_ < (IVEND) - 1) {                                                       \
      const _Float16* wb = wpk4 + (size_t)(iv_ + 1) * 16384 + og * 2048 + lane * 8;\
      BNXT[0] = *(const half8*)(wb);                                               \
      BNXT[1] = *(const half8*)(wb + 512);                                         \
      BNXT[2] = *(const half8*)(wb + 1024);                                        \
      BNXT[3] = *(const half8*)(wb + 1536);                                        \
      int chunk = 2 * (iv_ + 1) + sub;                                             \
      int tap = chunk >> 3, cg = chunk & 7;                                        \
      int4 ncb = cbl[gpx][tap]; float4 ncw = cwl[gpx][tap];                        \
      pre[0] = *(const half8*)(xtb + (size_t)ncb.x + cg * 32 + ko);                \
      pre[1] = *(const half8*)(xtb + (size_t)ncb.y + cg * 32 + ko);                \
      pre[2] = *(const half8*)(xtb + (size_t)ncb.z + cg * 32 + ko);                \
      pre[3] = *(const half8*)(xtb + (size_t)ncb.w + cg * 32 + ko);                \
      cwa[0] = ncw.x; cwa[1] = ncw.y; cwa[2] = ncw.z; cwa[3] = ncw.w;              \
    }                                                                              \
    __builtin_amdgcn_s_setprio(1);                                                 \
    _Pragma("unroll")                                                              \
    for (int mm = 0; mm < 4; ++mm) {                                               \
      half8 a0 = *(const half8*)&Ab[RBUF][(mm * 16 + lm) * AST + kg8];             \
      half8 a1 = *(const half8*)&Ab[RBUF][(mm * 16 + lm) * AST + 32 + kg8];        \
      acc[mm][0] = __builtin_amdgcn_mfma_f32_16x16x32_f16(a0, BCUR[0], acc[mm][0], 0, 0, 0); \
      acc[mm][1] = __builtin_amdgcn_mfma_f32_16x16x32_f16(a0, BCUR[1], acc[mm][1], 0, 0, 0); \
      acc[mm][0] = __builtin_amdgcn_mfma_f32_16x16x32_f16(a1, BCUR[2], acc[mm][0], 0, 0, 0); \
      acc[mm][1] = __builtin_amdgcn_mfma_f32_16x16x32_f16(a1, BCUR[3], acc[mm][1], 0, 0, 0); \
    }                                                                              \
    __builtin_amdgcn_s_setprio(0);                                                 \
    if (iv_ < (IVEND) - 1) {                                                       \
      half8 v = pre[0] * (_Float16)cwa[0];                                         \
      v += pre[1] * (_Float16)cwa[1];                                              \
      v += pre[2] * (_Float16)cwa[2];                                              \
      v += pre[3] * (_Float16)cwa[3];                                              \
      *(half8*)&Ab[WBUF][gpx * AST + cq * 8] = v;                                  \
    }                                                                              \
  }

// ---------------- split-K gather+GEMM: grid (400,2), writes f16 partials ----------------
// launch_bounds (512,4): R10's (512,6) capped VGPR at 40 -> massive scratch spill
// (FETCH 441 MB, WRITE 695 MB). 4 waves/EU keeps the proven 64-VGPR allocation.
__global__ __launch_bounds__(512, 4) void k_main_sk(const _Float16* __restrict__ xt,
                                                    const _Float16* __restrict__ wpk4,
                                                    const float* __restrict__ off4,
                                                    const float* __restrict__ obias,
                                                    _Float16* __restrict__ P) {
    __shared__ _Float16 Ab[2][PXB * AST];   // 18432 B
    __shared__ int4     cbl[PXB][KK];       // 9216 B
    __shared__ float4   cwl[PXB][KK];       // 9216 B

    int t = threadIdx.x, lane = t & 63, og = t >> 6;
    int lm = lane & 15, kg8 = (lane >> 4) * 8;
    int ksl = blockIdx.y;
    int iv0 = ksl * (NIV / 2);
    int tile = ((int)blockIdx.x & 7) * (NBLK / 8) + ((int)blockIdx.x >> 3);
    int pixbase = tile * PXB;
    int bb = pixbase / HW, hw0 = pixbase % HW;
    const _Float16* xtb = xt + (size_t)bb * HW * CH;

    build_corners(t, 512, pixbase, off4, obias, cbl, cwl);
    __syncthreads();

    int gpx = t >> 3, cq = t & 7;
    int sub = cq >> 2, ko = (cq & 3) * 8;

    // prologue: B(iv0) -> regs; gather interval iv0 -> Ab[0]
    half8 bfA[4], bfB[4];
    {
        const _Float16* wb = wpk4 + (size_t)iv0 * 16384 + og * 2048 + lane * 8;
        bfA[0] = *(const half8*)(wb);
        bfA[1] = *(const half8*)(wb + 512);
        bfA[2] = *(const half8*)(wb + 1024);
        bfA[3] = *(const half8*)(wb + 1536);
    }
    {
        int chunk0 = 2 * iv0 + sub;
        int tap0 = chunk0 >> 3, cg0 = chunk0 & 7;
        int4 cb = cbl[gpx][tap0];
        float4 cw = cwl[gpx][tap0];
        half8 v = *(const half8*)(xtb + (size_t)cb.x + cg0 * 32 + ko) * (_Float16)cw.x;
        v += *(const half8*)(xtb + (size_t)cb.y + cg0 * 32 + ko) * (_Float16)cw.y;
        v += *(const half8*)(xtb + (size_t)cb.z + cg0 * 32 + ko) * (_Float16)cw.z;
        v += *(const half8*)(xtb + (size_t)cb.w + cg0 * 32 + ko) * (_Float16)cw.w;
        *(half8*)&Ab[0][gpx * AST + cq * 8] = v;
    }

    f32x4 acc[4][2];
    #pragma unroll
    for (int mm = 0; mm < 4; ++mm) {
        acc[mm][0] = (f32x4)0.f;
        acc[mm][1] = (f32x4)0.f;
    }

    int ivend = iv0 + NIV / 2;
    for (int ii = iv0; ii < ivend; ii += 2) {
        BODY(ii,     ivend, bfA, bfB, 0, 1)
        BODY(ii + 1, ivend, bfB, bfA, 1, 0)
    }

    // --- write f16 partials, NCHW-flat plane ksl ---
    _Float16* Pb = P + (size_t)ksl * NPIX * CH + (size_t)bb * CH * HW;
    #pragma unroll
    for (int nn = 0; nn < 2; ++nn) {
        int oc = og * 32 + nn * 16 + lm;
        _Float16* prow = Pb + (size_t)oc * HW + hw0;
        #pragma unroll
        for (int mm = 0; mm < 4; ++mm) {
            int pb2 = mm * 16 + (lane >> 4) * 4;
            half4 h = {(_Float16)acc[mm][nn][0], (_Float16)acc[mm][nn][1],
                       (_Float16)acc[mm][nn][2], (_Float16)acc[mm][nn][3]};
            *(half4*)&prow[pb2] = h;
        }
    }
}

// ---------------- finish: reduce halves + BN + SiLU + residual ----------------
__global__ __launch_bounds__(512) void k_finish(const _Float16* __restrict__ P,
                                                const float* __restrict__ x,
                                                const float* __restrict__ gamma,
                                                const float* __restrict__ beta,
                                                const float* __restrict__ mean,
                                                const float* __restrict__ var,
                                                float* __restrict__ out) {
    int tid = blockIdx.x * 512 + threadIdx.x;       // 819200 threads
    size_t base = (size_t)tid * 8;
    int oc = (tid / (HW / 8)) & (CH - 1);
    half8 p0 = *(const half8*)(P + base);
    half8 p1 = *(const half8*)(P + (size_t)NPIX * CH + base);
    float sc = gamma[oc] * rsqrtf(var[oc] + 1e-5f);
    float mn = mean[oc], bt = beta[oc];
    float4 x0 = *(const float4*)(x + base);
    float4 x1 = *(const float4*)(x + base + 4);
    float o[8];
    #pragma unroll
    for (int j = 0; j < 8; ++j) {
        float y = (float)p0[j] + (float)p1[j];
        float yv = (y - mn) * sc + bt;
        float s = yv * __builtin_amdgcn_rcpf(1.f + __expf(-yv));
        float xv = (j < 4) ? ((const float*)&x0)[j] : ((const float*)&x1)[j - 4];
        o[j] = xv + s;
    }
    *(float4*)(out + base)     = make_float4(o[0], o[1], o[2], o[3]);
    *(float4*)(out + base + 4) = make_float4(o[4], o[5], o[6], o[7]);
}

// ---------------- fallback: R9 fused kernel (single-pass, fused epilogue) ----------------
__global__ __launch_bounds__(512, 4) void k_main_fused(const float* __restrict__ x,
                                                       const _Float16* __restrict__ xt,
                                                       const _Float16* __restrict__ wpk4,
                                                       const float* __restrict__ off4,
                                                       const float* __restrict__ obias,
                                                       const float* __restrict__ gamma,
                                                       const float* __restrict__ beta,
                                                       const float* __restrict__ mean,
                                                       const float* __restrict__ var,
                                                       float* __restrict__ out) {
    __shared__ _Float16 Ab[2][PXB * AST];
    __shared__ int4     cbl[PXB][KK];
    __shared__ float4   cwl[PXB][KK];

    int t = threadIdx.x, lane = t & 63, og = t >> 6;
    int lm = lane & 15, kg8 = (lane >> 4) * 8;
    int tile = ((int)blockIdx.x & 7) * (NBLK / 8) + ((int)blockIdx.x >> 3);
    int pixbase = tile * PXB;
    int bb = pixbase / HW, hw0 = pixbase % HW;
    const _Float16* xtb = xt + (size_t)bb * HW * CH;

    build_corners(t, 512, pixbase, off4, obias, cbl, cwl);
    __syncthreads();

    int gpx = t >> 3, cq = t & 7;
    int sub = cq >> 2, ko = (cq & 3) * 8;

    half8 bfA[4], bfB[4];
    {
        const _Float16* wb = wpk4 + og * 2048 + lane * 8;
        bfA[0] = *(const half8*)(wb);
        bfA[1] = *(const half8*)(wb + 512);
        bfA[2] = *(const half8*)(wb + 1024);
        bfA[3] = *(const half8*)(wb + 1536);
    }
    {
        int4 cb = cbl[gpx][0];
        float4 cw = cwl[gpx][0];
        int cg = sub;
        half8 v = *(const half8*)(xtb + (size_t)cb.x + cg * 32 + ko) * (_Float16)cw.x;
        v += *(const half8*)(xtb + (size_t)cb.y + cg * 32 + ko) * (_Float16)cw.y;
        v += *(const half8*)(xtb + (size_t)cb.z + cg * 32 + ko) * (_Float16)cw.z;
        v += *(const half8*)(xtb + (size_t)cb.w + cg * 32 + ko) * (_Float16)cw.w;
        *(half8*)&Ab[0][gpx * AST + cq * 8] = v;
    }

    f32x4 acc[4][2];
    #pragma unroll
    for (int mm = 0; mm < 4; ++mm) {
        acc[mm][0] = (f32x4)0.f;
        acc[mm][1] = (f32x4)0.f;
    }

    for (int ii = 0; ii < NIV; ii += 2) {
        BODY(ii,     NIV, bfA, bfB, 0, 1)
        BODY(ii + 1, NIV, bfB, bfA, 1, 0)
    }

    const float* xb2  = x   + (size_t)bb * CH * HW;
    float*       outb = out + (size_t)bb * CH * HW;
    #pragma unroll
    for (int nn = 0; nn < 2; ++nn) {
        int oc = og * 32 + nn * 16 + lm;
        float sc = gamma[oc] * rsqrtf(var[oc] + 1e-5f);
        float mn = mean[oc], bt = beta[oc];
        const float* xr   = xb2  + (size_t)oc * HW + hw0;
        float*       orow = outb + (size_t)oc * HW + hw0;
        #pragma unroll
        for (int mm = 0; mm < 4; ++mm) {
            int pb2 = mm * 16 + (lane >> 4) * 4;
            #pragma unroll
            for (int r = 0; r < 4; ++r) {
                float yv = (acc[mm][nn][r] - mn) * sc + bt;
                float s = yv * __builtin_amdgcn_rcpf(1.f + __expf(-yv));
                orow[pb2 + r] = xr[pb2 + r] + s;
            }
        }
    }
}

extern "C" void kernel_launch(void* const* d_in, const int* in_sizes, int n_in,
                              void* d_out, int out_size, void* d_ws, size_t ws_size,
                              hipStream_t stream) {
    const float* x        = (const float*)d_in[0];
    const float* offset_w = (const float*)d_in[1];
    const float* offset_b = (const float*)d_in[2];
    const float* dcn_w    = (const float*)d_in[3];
    const float* gamma    = (const float*)d_in[4];
    const float* beta     = (const float*)d_in[5];
    const float* mean     = (const float*)d_in[6];
    const float* var      = (const float*)d_in[7];
    float* out = (float*)d_out;

    _Float16* xt   = (_Float16*)d_ws;                         // 13,107,200 B
    _Float16* wpk4 = xt + (size_t)NPIX * CH;                  //  1,179,648 B
    _Float16* wopf = wpk4 + (size_t)NIV * 16384;              //    147,456 B
    float*    off4 = (float*)(wopf + (size_t)NCHUNK * 1024);  //  7,372,800 B
    _Float16* P    = (_Float16*)(off4 + (size_t)4 * NPIX * CO); // 26,214,400 B

    const size_t NEED = 13107200ull + 1179648 + 147456 + 7372800 + 26214400;

    k_transpose_x<<<dim3(HW / 32, CH / 32, BATCH), dim3(32, 8), 0, stream>>>(x, xt);
    k_pack_all<<<(NIV * 16384 + NCHUNK * 1024 + 255) / 256, 256, 0, stream>>>(dcn_w, offset_w, wpk4, wopf);
    k_offset<<<dim3(NBLK, 4), 256, 0, stream>>>(xt, wopf, off4);

    if (ws_size >= NEED) {
        k_main_sk<<<dim3(NBLK, 2), 512, 0, stream>>>(xt, wpk4, off4, offset_b, P);
        k_finish<<<(NPIX * CH / 8 + 511) / 512, 512, 0, stream>>>(P, x, gamma, beta, mean, var, out);
    } else {
        k_main_fused<<<NBLK, 512, 0, stream>>>(x, xt, wpk4, off4, offset_b,
                                               gamma, beta, mean, var, out);
    }
}

// Round 12
// 111.174 us; speedup vs baseline: 3.1340x; 1.0017x over previous
//
#include <hip/hip_runtime.h>
#include <math.h>
#include <stdint.h>

#define BATCH 4
#define CH    256
#define HH    80
#define WW    80
#define HW    (HH*WW)        // 6400
#define NPIX  (BATCH*HW)     // 25600
#define KK    9
#define CO    18             // 2*K*K offset channels
#define NCHUNK 72            // 9 taps * 8 groups of 32 channels
#define NIV   36             // K=64 intervals
#define PXB   32             // pixels per k_main block
#define NBLK  (NPIX/PXB)     // 800 blocks
#define AST   72             // A LDS row stride in halves (144 B)

typedef _Float16 half8 __attribute__((ext_vector_type(8)));
typedef float    f32x4 __attribute__((ext_vector_type(4)));

// ---------------- x NCHW f32 -> xt NHWC f16 ----------------
__global__ __launch_bounds__(256) void k_transpose_x(const float* __restrict__ x,
                                                     _Float16* __restrict__ xt) {
    __shared__ float tile[32][33];
    int b  = blockIdx.z;
    int c0 = blockIdx.y * 32;
    int p0 = blockIdx.x * 32;
    int tx = threadIdx.x;   // 0..31
    int ty = threadIdx.y;   // 0..7
    const float* xb = x + (size_t)b * CH * HW;
    #pragma unroll
    for (int i = 0; i < 32; i += 8)
        tile[ty + i][tx] = xb[(size_t)(c0 + ty + i) * HW + p0 + tx];
    __syncthreads();
    _Float16* xtb = xt + (size_t)b * HW * CH;
    #pragma unroll
    for (int i = 0; i < 32; i += 8)
        xtb[(size_t)(p0 + ty + i) * CH + c0 + tx] = (_Float16)tile[tx][ty + i];
}

// -------- combined weight pack --------
// dcn_w -> wpk4 [NIV][8 og][2 ks][2 nn][64 lane][8 e] f16 ; offset_w -> wopf
__global__ __launch_bounds__(256) void k_pack_all(const float* __restrict__ w,
                                                  const float* __restrict__ ow,
                                                  _Float16* __restrict__ wp,
                                                  _Float16* __restrict__ wpo) {
    int idx = blockIdx.x * 256 + threadIdx.x;
    if (idx < NIV * 16384) {
        int e    = idx & 7;
        int lane = (idx >> 3) & 63;
        int nn   = (idx >> 9) & 1;
        int ks   = (idx >> 10) & 1;
        int og   = (idx >> 11) & 7;
        int iv   = idx >> 14;
        int oc = og * 32 + nn * 16 + (lane & 15);
        int kl = ks * 32 + (lane >> 4) * 8 + e;
        int kg = iv * 64 + kl;
        int q  = kg >> 5;
        int tap = q >> 3;
        int c   = (q & 7) * 32 + (kg & 31);
        wp[idx] = (_Float16)w[((size_t)oc * CH + c) * KK + tap];
        return;
    }
    int idx2 = idx - NIV * 16384;
    if (idx2 >= NCHUNK * 1024) return;
    int e    = idx2 & 7;
    int lane = (idx2 >> 3) & 63;
    int nf   = (idx2 >> 9) & 1;
    int q    = idx2 >> 10;
    int oc  = nf * 16 + (lane & 15);
    int kic = (lane >> 4) * 8 + e;
    int tap = q >> 3;
    int c   = (q & 7) * 32 + kic;
    float v = (oc < CO) ? ow[((size_t)oc * CH + c) * KK + tap] : 0.f;
    wpo[idx2] = (_Float16)v;
}

// ---------------- offset conv via MFMA, barrier-free, K-split x4 ----------------
__global__ __launch_bounds__(256) void k_offset(const _Float16* __restrict__ xt,
                                                const _Float16* __restrict__ wopf,
                                                float* __restrict__ off4) {
    int t = threadIdx.x, lane = t & 63, wvi = t >> 6;
    int lm = lane & 15, kg8 = (lane >> 4) * 8;
    int ksl = blockIdx.y;
    int pixbase = blockIdx.x * 64;
    int bb = pixbase / HW;
    int apx = pixbase % HW + wvi * 16 + lm;
    int h = apx / WW, w = apx % WW;
    const _Float16* xtb = xt + (size_t)bb * HW * CH;
    f32x4 acc0 = (f32x4)0.f, acc1 = (f32x4)0.f;
    #pragma unroll
    for (int qq = 0; qq < 18; ++qq) {
        int q = ksl * 18 + qq;
        int tap = q >> 3, cg = q & 7;
        int ki = tap / 3, kj = tap % 3;
        int yy = h + ki - 1, xx = w + kj - 1;
        bool ok = (yy >= 0) && (yy < HH) && (xx >= 0) && (xx < WW);
        int yc = min(max(yy, 0), HH - 1), xc = min(max(xx, 0), WW - 1);
        half8 a = {0, 0, 0, 0, 0, 0, 0, 0};
        if (ok) a = *(const half8*)(xtb + (size_t)(yc * WW + xc) * CH + cg * 32 + kg8);
        const _Float16* wb = wopf + (size_t)q * 1024 + lane * 8;
        half8 b0 = *(const half8*)(wb);
        half8 b1 = *(const half8*)(wb + 512);
        acc0 = __builtin_amdgcn_mfma_f32_16x16x32_f16(a, b0, acc0, 0, 0, 0);
        acc1 = __builtin_amdgcn_mfma_f32_16x16x32_f16(a, b1, acc1, 0, 0, 0);
    }
    float* op = off4 + (size_t)ksl * NPIX * CO;
    int prow = (lane >> 4) * 4;
    #pragma unroll
    for (int r = 0; r < 4; ++r) {
        int pix = pixbase + wvi * 16 + prow + r;
        op[(size_t)pix * CO + lm] = acc0[r];
        if (lm < CO - 16) op[(size_t)pix * CO + 16 + lm] = acc1[r];
    }
}

// ---------------- fused gather + MFMA GEMM + BN/SiLU/residual ----------------
// 256 thr = 4 waves; block = 32 px x 256 oc; wave wvi owns oc [64*wvi, 64*wvi+64), full K.
// B read per-wave direct from L2 (no LDS, no reg-dbuf); A LDS-dbuf; corners in LDS.
// 4 independent blocks/CU cover each other's latency (launch_bounds (256,4) -> <=128 VGPR).
__global__ __launch_bounds__(256, 4) void k_main(const float* __restrict__ x,
                                                 const _Float16* __restrict__ xt,
                                                 const _Float16* __restrict__ wpk4,
                                                 const float* __restrict__ off4,
                                                 const float* __restrict__ obias,
                                                 const float* __restrict__ gamma,
                                                 const float* __restrict__ beta,
                                                 const float* __restrict__ mean,
                                                 const float* __restrict__ var,
                                                 float* __restrict__ out) {
    __shared__ _Float16 Ab[2][PXB * AST];   // 9216 B
    __shared__ int4     cbl[PXB][KK];       // 4608 B
    __shared__ float4   cwl[PXB][KK];       // 4608 B

    int t = threadIdx.x, lane = t & 63, wvi = t >> 6;
    int lm = lane & 15, kg8 = (lane >> 4) * 8;
    // bijective XCD swizzle (800 % 8 == 0)
    int tile = ((int)blockIdx.x & 7) * (NBLK / 8) + ((int)blockIdx.x >> 3);
    int pixbase = tile * PXB;
    int bb = pixbase / HW, hw0 = pixbase % HW;
    const _Float16* xtb = xt + (size_t)bb * HW * CH;

    // ---- corners/weights for 32 px x 9 taps -> LDS ----
    for (int task = t; task < PXB * KK; task += 256) {
        int p = task / KK, tap = task - (task / KK) * KK;
        int pix = pixbase + p;
        float dy = obias[2 * tap], dx = obias[2 * tap + 1];
        #pragma unroll
        for (int ks = 0; ks < 4; ++ks) {
            dy += off4[(size_t)ks * NPIX * CO + (size_t)pix * CO + 2 * tap];
            dx += off4[(size_t)ks * NPIX * CO + (size_t)pix * CO + 2 * tap + 1];
        }
        int hw = pix % HW, hc = hw / WW, wc = hw % WW;
        int ki = tap / 3, kj = tap % 3;
        float py = dy + (float)(hc - 1 + ki);
        float px = dx + (float)(wc - 1 + kj);
        float y0f = floorf(py), x0f = floorf(px);
        float wy = py - y0f, wx = px - x0f;
        int y0 = (int)y0f, x0 = (int)x0f;
        int cb[4]; float cw[4];
        #pragma unroll
        for (int cy = 0; cy < 2; ++cy)
            #pragma unroll
            for (int cx = 0; cx < 2; ++cx) {
                int yy = y0 + cy, xx = x0 + cx;
                bool okc = (yy >= 0) && (yy < HH) && (xx >= 0) && (xx < WW);
                int yc = min(max(yy, 0), HH - 1);
                int xc = min(max(xx, 0), WW - 1);
                float wgt = (cy ? wy : 1.f - wy) * (cx ? wx : 1.f - wx);
                cb[cy * 2 + cx] = (yc * WW + xc) * CH;
                cw[cy * 2 + cx] = okc ? wgt : 0.f;
            }
        cbl[p][tap] = make_int4(cb[0], cb[1], cb[2], cb[3]);
        cwl[p][tap] = make_float4(cw[0], cw[1], cw[2], cw[3]);
    }
    __syncthreads();

    int gpx = t >> 3, cq = t & 7;          // gather role: pixel gpx, slot cq
    int sub = cq >> 2, ko = (cq & 3) * 8;  // chunk-within-interval, channel quad

    // prologue: gather interval 0 (chunks 0,1) -> Ab[0]
    {
        int4 cb = cbl[gpx][0];
        float4 cw = cwl[gpx][0];
        int cg = sub;                       // chunks 0,1: tap 0
        half8 v = *(const half8*)(xtb + (size_t)cb.x + cg * 32 + ko) * (_Float16)cw.x;
        v += *(const half8*)(xtb + (size_t)cb.y + cg * 32 + ko) * (_Float16)cw.y;
        v += *(const half8*)(xtb + (size_t)cb.z + cg * 32 + ko) * (_Float16)cw.z;
        v += *(const half8*)(xtb + (size_t)cb.w + cg * 32 + ko) * (_Float16)cw.w;
        *(half8*)&Ab[0][gpx * AST + cq * 8] = v;
    }

    f32x4 acc[2][4];
    #pragma unroll
    for (int mm = 0; mm < 2; ++mm)
        #pragma unroll
        for (int nn = 0; nn < 4; ++nn) acc[mm][nn] = (f32x4)0.f;

    for (int i = 0; i < NIV; ++i) {
        int buf = i & 1;
        __syncthreads();

        // B fragments: per-wave direct L2 reads (issued first, consumed after af loads)
        half8 bf[2][4];
        {
            const _Float16* wb = wpk4 + (size_t)i * 16384 + (wvi * 2) * 2048 + lane * 8;
            #pragma unroll
            for (int og2 = 0; og2 < 2; ++og2)
                #pragma unroll
                for (int ks = 0; ks < 2; ++ks)
                    #pragma unroll
                    for (int nn = 0; nn < 2; ++nn)
                        bf[ks][og2 * 2 + nn] = *(const half8*)(wb + og2 * 2048 + ks * 1024 + nn * 512);
        }

        // prefetch next-interval gather loads
        half8 pre[4];
        float cwa[4];
        if (i < NIV - 1) {
            int chunk = 2 * (i + 1) + sub;
            int tap = chunk >> 3, cg = chunk & 7;
            int4 ncb = cbl[gpx][tap];
            float4 ncw = cwl[gpx][tap];
            pre[0] = *(const half8*)(xtb + (size_t)ncb.x + cg * 32 + ko);
            pre[1] = *(const half8*)(xtb + (size_t)ncb.y + cg * 32 + ko);
            pre[2] = *(const half8*)(xtb + (size_t)ncb.z + cg * 32 + ko);
            pre[3] = *(const half8*)(xtb + (size_t)ncb.w + cg * 32 + ko);
            cwa[0] = ncw.x; cwa[1] = ncw.y; cwa[2] = ncw.z; cwa[3] = ncw.w;
        }

        // A fragments from LDS
        half8 af[2][2];
        #pragma unroll
        for (int mm = 0; mm < 2; ++mm)
            #pragma unroll
            for (int ks = 0; ks < 2; ++ks)
                af[mm][ks] = *(const half8*)&Ab[buf][(mm * 16 + lm) * AST + ks * 32 + kg8];

        __builtin_amdgcn_s_setprio(1);
        #pragma unroll
        for (int ks = 0; ks < 2; ++ks)
            #pragma unroll
            for (int mm = 0; mm < 2; ++mm)
                #pragma unroll
                for (int nn = 0; nn < 4; ++nn)
                    acc[mm][nn] = __builtin_amdgcn_mfma_f32_16x16x32_f16(af[mm][ks], bf[ks][nn], acc[mm][nn], 0, 0, 0);
        __builtin_amdgcn_s_setprio(0);

        // blend + write next A (write-late)
        if (i < NIV - 1) {
            half8 v = pre[0] * (_Float16)cwa[0];
            v += pre[1] * (_Float16)cwa[1];
            v += pre[2] * (_Float16)cwa[2];
            v += pre[3] * (_Float16)cwa[3];
            *(half8*)&Ab[buf ^ 1][gpx * AST + cq * 8] = v;
        }
    }

    // --- epilogue: BN + SiLU + residual ---
    const float* xb2  = x   + (size_t)bb * CH * HW;
    float*       outb = out + (size_t)bb * CH * HW;
    #pragma unroll
    for (int nn = 0; nn < 4; ++nn) {
        int oc = wvi * 64 + nn * 16 + lm;
        float sc = gamma[oc] * rsqrtf(var[oc] + 1e-5f);
        float mn = mean[oc], bt = beta[oc];
        const float* xr   = xb2  + (size_t)oc * HW + hw0;
        float*       orow = outb + (size_t)oc * HW + hw0;
        #pragma unroll
        for (int mm = 0; mm < 2; ++mm) {
            int pb2 = mm * 16 + (lane >> 4) * 4;
            #pragma unroll
            for (int r = 0; r < 4; ++r) {
                float yv = (acc[mm][nn][r] - mn) * sc + bt;
                float s = yv * __builtin_amdgcn_rcpf(1.f + __expf(-yv));
                orow[pb2 + r] = xr[pb2 + r] + s;
            }
        }
    }
}

extern "C" void kernel_launch(void* const* d_in, const int* in_sizes, int n_in,
                              void* d_out, int out_size, void* d_ws, size_t ws_size,
                              hipStream_t stream) {
    const float* x        = (const float*)d_in[0];
    const float* offset_w = (const float*)d_in[1];
    const float* offset_b = (const float*)d_in[2];
    const float* dcn_w    = (const float*)d_in[3];
    const float* gamma    = (const float*)d_in[4];
    const float* beta     = (const float*)d_in[5];
    const float* mean     = (const float*)d_in[6];
    const float* var      = (const float*)d_in[7];
    float* out = (float*)d_out;

    _Float16* xt   = (_Float16*)d_ws;                         // 13,107,200 B
    _Float16* wpk4 = xt + (size_t)NPIX * CH;                  //  1,179,648 B
    _Float16* wopf = wpk4 + (size_t)NIV * 16384;              //    147,456 B
    float*    off4 = (float*)(wopf + (size_t)NCHUNK * 1024);  //  7,372,800 B

    k_transpose_x<<<dim3(HW / 32, CH / 32, BATCH), dim3(32, 8), 0, stream>>>(x, xt);
    k_pack_all<<<(NIV * 16384 + NCHUNK * 1024 + 255) / 256, 256, 0, stream>>>(dcn_w, offset_w, wpk4, wopf);
    k_offset<<<dim3(NPIX / 64, 4), 256, 0, stream>>>(xt, wopf, off4);
    k_main<<<NBLK, 256, 0, stream>>>(x, xt, wpk4, off4, offset_b,
                                     gamma, beta, mean, var, out);
}

// Round 13
// 91.923 us; speedup vs baseline: 3.7903x; 1.2094x over previous
//
#include <hip/hip_runtime.h>
#include <math.h>
#include <stdint.h>

#define BATCH 4
#define CH    256
#define HH    80
#define WW    80
#define HW    (HH*WW)        // 6400
#define NPIX  (BATCH*HW)     // 25600
#define KK    9
#define CO    18             // 2*K*K offset channels
#define NCHUNK 72            // 9 taps * 8 groups of 32 channels
#define NIV   36             // K=64 intervals
#define PXB   64             // pixels per k_main block
#define NBLK  (NPIX/PXB)     // 400 blocks
#define AST   72             // A LDS row stride in halves (144 B)

typedef _Float16 half8 __attribute__((ext_vector_type(8)));
typedef float    f32x4 __attribute__((ext_vector_type(4)));

// ---------------- x NCHW f32 -> xt NHWC f16 ----------------
__global__ __launch_bounds__(256) void k_transpose_x(const float* __restrict__ x,
                                                     _Float16* __restrict__ xt) {
    __shared__ float tile[32][33];
    int b  = blockIdx.z;
    int c0 = blockIdx.y * 32;
    int p0 = blockIdx.x * 32;
    int tx = threadIdx.x;   // 0..31
    int ty = threadIdx.y;   // 0..7
    const float* xb = x + (size_t)b * CH * HW;
    #pragma unroll
    for (int i = 0; i < 32; i += 8)
        tile[ty + i][tx] = xb[(size_t)(c0 + ty + i) * HW + p0 + tx];
    __syncthreads();
    _Float16* xtb = xt + (size_t)b * HW * CH;
    #pragma unroll
    for (int i = 0; i < 32; i += 8)
        xtb[(size_t)(p0 + ty + i) * CH + c0 + tx] = (_Float16)tile[tx][ty + i];
}

// -------- combined weight pack --------
// dcn_w -> wpk4 [NIV][8 og][2 ks][2 nn][64 lane][8 e] f16 ; offset_w -> wopf [72 q][2 nf][64][8]
__global__ __launch_bounds__(256) void k_pack_all(const float* __restrict__ w,
                                                  const float* __restrict__ ow,
                                                  _Float16* __restrict__ wp,
                                                  _Float16* __restrict__ wpo) {
    int idx = blockIdx.x * 256 + threadIdx.x;
    if (idx < NIV * 16384) {
        int e    = idx & 7;
        int lane = (idx >> 3) & 63;
        int nn   = (idx >> 9) & 1;
        int ks   = (idx >> 10) & 1;
        int og   = (idx >> 11) & 7;
        int iv   = idx >> 14;
        int oc = og * 32 + nn * 16 + (lane & 15);
        int kl = ks * 32 + (lane >> 4) * 8 + e;
        int kg = iv * 64 + kl;
        int q  = kg >> 5;
        int tap = q >> 3;
        int c   = (q & 7) * 32 + (kg & 31);
        wp[idx] = (_Float16)w[((size_t)oc * CH + c) * KK + tap];
        return;
    }
    int idx2 = idx - NIV * 16384;
    if (idx2 >= NCHUNK * 1024) return;
    int e    = idx2 & 7;
    int lane = (idx2 >> 3) & 63;
    int nf   = (idx2 >> 9) & 1;
    int q    = idx2 >> 10;
    int oc  = nf * 16 + (lane & 15);
    int kic = (lane >> 4) * 8 + e;
    int tap = q >> 3;
    int c   = (q & 7) * 32 + kic;
    float v = (oc < CO) ? ow[((size_t)oc * CH + c) * KK + tap] : 0.f;
    wpo[idx2] = (_Float16)v;
}

// ---- interval body: B reg-dbuf + A LDS-dbuf, one barrier (R9-proven) ----
#define BODY(IV, IVEND, BCUR, BNXT, RBUF, WBUF)                                    \
  {                                                                                \
    __syncthreads();                                                               \
    const int iv_ = (IV);                                                          \
    half8 pre[4]; float cwa[4];                                                    \
    if (iv_ < (IVEND) - 1) {                                                       \
      const _Float16* wb = wpk4 + (size_t)(iv_ + 1) * 16384 + og * 2048 + lane * 8;\
      BNXT[0] = *(const half8*)(wb);                                               \
      BNXT[1] = *(const half8*)(wb + 512);                                         \
      BNXT[2] = *(const half8*)(wb + 1024);                                        \
      BNXT[3] = *(const half8*)(wb + 1536);                                        \
      int chunk = 2 * (iv_ + 1) + sub;                                             \
      int tap = chunk >> 3, cg = chunk & 7;                                        \
      int4 ncb = cbl[gpx][tap]; float4 ncw = cwl[gpx][tap];                        \
      pre[0] = *(const half8*)(xtb + (size_t)ncb.x + cg * 32 + ko);                \
      pre[1] = *(const half8*)(xtb + (size_t)ncb.y + cg * 32 + ko);                \
      pre[2] = *(const half8*)(xtb + (size_t)ncb.z + cg * 32 + ko);                \
      pre[3] = *(const half8*)(xtb + (size_t)ncb.w + cg * 32 + ko);                \
      cwa[0] = ncw.x; cwa[1] = ncw.y; cwa[2] = ncw.z; cwa[3] = ncw.w;              \
    }                                                                              \
    __builtin_amdgcn_s_setprio(1);                                                 \
    _Pragma("unroll")                                                              \
    for (int mm = 0; mm < 4; ++mm) {                                               \
      half8 a0 = *(const half8*)&Ab[RBUF][(mm * 16 + lm) * AST + kg8];             \
      half8 a1 = *(const half8*)&Ab[RBUF][(mm * 16 + lm) * AST + 32 + kg8];        \
      acc[mm][0] = __builtin_amdgcn_mfma_f32_16x16x32_f16(a0, BCUR[0], acc[mm][0], 0, 0, 0); \
      acc[mm][1] = __builtin_amdgcn_mfma_f32_16x16x32_f16(a0, BCUR[1], acc[mm][1], 0, 0, 0); \
      acc[mm][0] = __builtin_amdgcn_mfma_f32_16x16x32_f16(a1, BCUR[2], acc[mm][0], 0, 0, 0); \
      acc[mm][1] = __builtin_amdgcn_mfma_f32_16x16x32_f16(a1, BCUR[3], acc[mm][1], 0, 0, 0); \
    }                                                                              \
    __builtin_amdgcn_s_setprio(0);                                                 \
    if (iv_ < (IVEND) - 1) {                                                       \
      half8 v = pre[0] * (_Float16)cwa[0];                                         \
      v += pre[1] * (_Float16)cwa[1];                                              \
      v += pre[2] * (_Float16)cwa[2];                                              \
      v += pre[3] * (_Float16)cwa[3];                                              \
      *(half8*)&Ab[WBUF][gpx * AST + cq * 8] = v;                                  \
    }                                                                              \
  }

// ---------------- fully-fused: offset-conv + corners + gather/GEMM + epilogue ----------------
// 512 thr = 8 waves. Phase 1: offset conv via MFMA, waves = (pxf 0-3) x (kh 0-1),
// wave computes 16px x 18oc over half the K chunks -> offl[kh]; corner build sums halves.
// Main loop: R9-proven (8 og-waves, B reg-dbuf, A LDS-dbuf, 1 barrier/interval).
__global__ __launch_bounds__(512, 4) void k_main(const float* __restrict__ x,
                                                 const _Float16* __restrict__ xt,
                                                 const _Float16* __restrict__ wpk4,
                                                 const _Float16* __restrict__ wopf,
                                                 const float* __restrict__ obias,
                                                 const float* __restrict__ gamma,
                                                 const float* __restrict__ beta,
                                                 const float* __restrict__ mean,
                                                 const float* __restrict__ var,
                                                 float* __restrict__ out) {
    __shared__ _Float16 Ab[2][PXB * AST];   // 18432 B
    __shared__ int4     cbl[PXB][KK];       // 9216 B
    __shared__ float4   cwl[PXB][KK];       // 9216 B
    __shared__ float    offl[2][PXB][CO];   // 9216 B   (total 46080 B)

    int t = threadIdx.x, lane = t & 63, og = t >> 6;
    int lm = lane & 15, kg8 = (lane >> 4) * 8;
    // bijective XCD swizzle (400 % 8 == 0)
    int tile = ((int)blockIdx.x & 7) * (NBLK / 8) + ((int)blockIdx.x >> 3);
    int pixbase = tile * PXB;
    int bb = pixbase / HW, hw0 = pixbase % HW;
    const _Float16* xtb = xt + (size_t)bb * HW * CH;

    // ---- phase 1: offset conv via MFMA ----
    {
        int pxf = og & 3, kh = og >> 2;
        int apx = hw0 + pxf * 16 + lm;         // A-row pixel (lm = px row for A-frag)
        int h = apx / WW, w = apx % WW;
        f32x4 oacc0 = (f32x4)0.f, oacc1 = (f32x4)0.f;
        #pragma unroll
        for (int qq = 0; qq < NCHUNK / 2; ++qq) {
            int q = kh * (NCHUNK / 2) + qq;
            int tap = q >> 3, cg = q & 7;
            int ki = tap / 3, kj = tap - ki * 3;
            int yy = h + ki - 1, xx = w + kj - 1;
            bool ok = (yy >= 0) && (yy < HH) && (xx >= 0) && (xx < WW);
            int yc = min(max(yy, 0), HH - 1), xc = min(max(xx, 0), WW - 1);
            half8 a = {0, 0, 0, 0, 0, 0, 0, 0};
            if (ok) a = *(const half8*)(xtb + (size_t)(yc * WW + xc) * CH + cg * 32 + kg8);
            const _Float16* wb = wopf + (size_t)q * 1024 + lane * 8;
            half8 b0 = *(const half8*)(wb);
            half8 b1 = *(const half8*)(wb + 512);
            oacc0 = __builtin_amdgcn_mfma_f32_16x16x32_f16(a, b0, oacc0, 0, 0, 0);
            oacc1 = __builtin_amdgcn_mfma_f32_16x16x32_f16(a, b1, oacc1, 0, 0, 0);
        }
        int prow = pxf * 16 + (lane >> 4) * 4;
        #pragma unroll
        for (int r = 0; r < 4; ++r) offl[kh][prow + r][lm] = oacc0[r];
        if (lm < CO - 16) {
            #pragma unroll
            for (int r = 0; r < 4; ++r) offl[kh][prow + r][16 + lm] = oacc1[r];
        }
    }
    __syncthreads();

    // ---- phase 2: bilinear corners/weights for 64 px x 9 taps -> LDS ----
    for (int task = t; task < PXB * KK; task += 512) {
        int p = task / KK, tap = task - (task / KK) * KK;
        float dy = offl[0][p][2 * tap]     + offl[1][p][2 * tap]     + obias[2 * tap];
        float dx = offl[0][p][2 * tap + 1] + offl[1][p][2 * tap + 1] + obias[2 * tap + 1];
        int hw = hw0 + p, hc = hw / WW, wc = hw % WW;
        int ki = tap / 3, kj = tap - ki * 3;
        float py = dy + (float)(hc - 1 + ki);
        float px = dx + (float)(wc - 1 + kj);
        float y0f = floorf(py), x0f = floorf(px);
        float wy = py - y0f, wx = px - x0f;
        int y0 = (int)y0f, x0 = (int)x0f;
        int cb[4]; float cw[4];
        #pragma unroll
        for (int cy = 0; cy < 2; ++cy)
            #pragma unroll
            for (int cx = 0; cx < 2; ++cx) {
                int yy = y0 + cy, xx = x0 + cx;
                bool okc = (yy >= 0) && (yy < HH) && (xx >= 0) && (xx < WW);
                int yc = min(max(yy, 0), HH - 1);
                int xc = min(max(xx, 0), WW - 1);
                float wgt = (cy ? wy : 1.f - wy) * (cx ? wx : 1.f - wx);
                cb[cy * 2 + cx] = (yc * WW + xc) * CH;
                cw[cy * 2 + cx] = okc ? wgt : 0.f;
            }
        cbl[p][tap] = make_int4(cb[0], cb[1], cb[2], cb[3]);
        cwl[p][tap] = make_float4(cw[0], cw[1], cw[2], cw[3]);
    }
    __syncthreads();

    int gpx = t >> 3, cq = t & 7;
    int sub = cq >> 2, ko = (cq & 3) * 8;

    // prologue: B(0) -> regs; gather interval 0 (chunks 0,1) -> Ab[0]
    half8 bfA[4], bfB[4];
    {
        const _Float16* wb = wpk4 + og * 2048 + lane * 8;
        bfA[0] = *(const half8*)(wb);
        bfA[1] = *(const half8*)(wb + 512);
        bfA[2] = *(const half8*)(wb + 1024);
        bfA[3] = *(const half8*)(wb + 1536);
    }
    {
        int4 cb = cbl[gpx][0];
        float4 cw = cwl[gpx][0];
        int cg = sub;                       // chunks 0,1: tap 0
        half8 v = *(const half8*)(xtb + (size_t)cb.x + cg * 32 + ko) * (_Float16)cw.x;
        v += *(const half8*)(xtb + (size_t)cb.y + cg * 32 + ko) * (_Float16)cw.y;
        v += *(const half8*)(xtb + (size_t)cb.z + cg * 32 + ko) * (_Float16)cw.z;
        v += *(const half8*)(xtb + (size_t)cb.w + cg * 32 + ko) * (_Float16)cw.w;
        *(half8*)&Ab[0][gpx * AST + cq * 8] = v;
    }

    f32x4 acc[4][2];
    #pragma unroll
    for (int mm = 0; mm < 4; ++mm) {
        acc[mm][0] = (f32x4)0.f;
        acc[mm][1] = (f32x4)0.f;
    }

    for (int ii = 0; ii < NIV; ii += 2) {
        BODY(ii,     NIV, bfA, bfB, 0, 1)
        BODY(ii + 1, NIV, bfB, bfA, 1, 0)
    }

    // --- epilogue: BN + SiLU + residual ---
    const float* xb2  = x   + (size_t)bb * CH * HW;
    float*       outb = out + (size_t)bb * CH * HW;
    #pragma unroll
    for (int nn = 0; nn < 2; ++nn) {
        int oc = og * 32 + nn * 16 + lm;
        float sc = gamma[oc] * rsqrtf(var[oc] + 1e-5f);
        float mn = mean[oc], bt = beta[oc];
        const float* xr   = xb2  + (size_t)oc * HW + hw0;
        float*       orow = outb + (size_t)oc * HW + hw0;
        #pragma unroll
        for (int mm = 0; mm < 4; ++mm) {
            int pb2 = mm * 16 + (lane >> 4) * 4;
            #pragma unroll
            for (int r = 0; r < 4; ++r) {
                float yv = (acc[mm][nn][r] - mn) * sc + bt;
                float s = yv * __builtin_amdgcn_rcpf(1.f + __expf(-yv));
                orow[pb2 + r] = xr[pb2 + r] + s;
            }
        }
    }
}

extern "C" void kernel_launch(void* const* d_in, const int* in_sizes, int n_in,
                              void* d_out, int out_size, void* d_ws, size_t ws_size,
                              hipStream_t stream) {
    const float* x        = (const float*)d_in[0];
    const float* offset_w = (const float*)d_in[1];
    const float* offset_b = (const float*)d_in[2];
    const float* dcn_w    = (const float*)d_in[3];
    const float* gamma    = (const float*)d_in[4];
    const float* beta     = (const float*)d_in[5];
    const float* mean     = (const float*)d_in[6];
    const float* var      = (const float*)d_in[7];
    float* out = (float*)d_out;

    _Float16* xt   = (_Float16*)d_ws;                    // 13,107,200 B
    _Float16* wpk4 = xt + (size_t)NPIX * CH;             //  1,179,648 B
    _Float16* wopf = wpk4 + (size_t)NIV * 16384;         //    147,456 B

    k_transpose_x<<<dim3(HW / 32, CH / 32, BATCH), dim3(32, 8), 0, stream>>>(x, xt);
    k_pack_all<<<(NIV * 16384 + NCHUNK * 1024 + 255) / 256, 256, 0, stream>>>(dcn_w, offset_w, wpk4, wopf);
    k_main<<<NBLK, 512, 0, stream>>>(x, xt, wpk4, wopf, offset_b,
                                     gamma, beta, mean, var, out);
}